// Round 6
// baseline (12374.501 us; speedup 1.0000x reference)
//
#include <hip/hip_runtime.h>
#include <stdint.h>

// Problem constants
#define BB   64
#define TT   250
#define INN  1024
#define HIDD 2048
#define OUTT 256

#define DECAYF 0.951229424500714f   // exp(-1/20)
#define ALPHAF 0.951229424500714f
#define LRF    1e-4f
#define WDF    0.01f
#define SCLF   0.2f

// block roles
#define N_L1   128               // w_in tiles [16h x 1024] bf16, LDS-resident
#define N_L2   16                // w_hid rows [16o x 2048] f32, global block-private
#define N_HELP 8                 // in_tr state in LDS; publishes in_tr^T and xbf
#define NBLK   152u

// d_out offsets (float elements), return order:
// l1_seq [64,250,2048], l2_seq [64,250,256], v1, v2, l1_tr, l2_tr
#define O_L1SEQ 0
#define O_L2SEQ 32768000
#define O_V1    36864000
#define O_V2    36995072
#define O_L1TR  37011456
#define O_L2TR  37142528

// workspace (byte offsets): cross-block data, accessed via agent-coherent ops
#define WS_XBF   0u        // bf16 [2][64][1024]   x_t bf16 (gemm1 A)
#define WS_INTRT 262144u   // bf16 [2][1024][64]   in_tr^T  (outer1 B)
#define WS_L1B   524288u   // bf16 [2][64][2048]   l1 spikes (gemm2 A)
#define WS_L1TRT 1048576u  // bf16 [2][2048][64]   l1_tr^T  (outer2 B)
#define WS_BAR   1572864u  // u32 monotonic barrier counter

typedef __attribute__((ext_vector_type(8))) short short8v;
typedef __attribute__((ext_vector_type(4))) float float4v;
typedef unsigned long long u64;

__device__ inline short f2bf(float f) {
  union { float f; uint32_t u; } c; c.f = f;
  uint32_t u = c.u + 0x7fffu + ((c.u >> 16) & 1u);  // RNE
  return (short)(u >> 16);
}
__device__ inline float bf2f(short s) {
  union { uint32_t u; float f; } c; c.u = ((uint32_t)(uint16_t)s) << 16;
  return c.f;
}

// ---- agent-coherent (LLC-point) accessors for cross-block buffers ----
__device__ inline u64 cld(const short* p) {
  return __hip_atomic_load((const u64*)p, __ATOMIC_RELAXED, __HIP_MEMORY_SCOPE_AGENT);
}
__device__ inline void cst(short* p, u64 v) {
  __hip_atomic_store((u64*)p, v, __ATOMIC_RELAXED, __HIP_MEMORY_SCOPE_AGENT);
}
__device__ inline void cst16(short* p, short v) {
  __hip_atomic_store((unsigned short*)p, (unsigned short)v,
                     __ATOMIC_RELAXED, __HIP_MEMORY_SCOPE_AGENT);
}
__device__ inline short8v mk8(u64 a, u64 b) {
  union { u64 u[2]; short8v s; } c; c.u[0] = a; c.u[1] = b; return c.s;
}

// ---- grid barrier: monotonic counter, no cache maintenance (R5-proven) ----
__device__ inline void gbar(unsigned* cnt, unsigned target, int tid) {
  asm volatile("s_waitcnt vmcnt(0)" ::: "memory");
  __syncthreads();
  if (tid == 0) {
    __hip_atomic_fetch_add(cnt, 1u, __ATOMIC_RELAXED, __HIP_MEMORY_SCOPE_AGENT);
    while (__hip_atomic_load(cnt, __ATOMIC_RELAXED, __HIP_MEMORY_SCOPE_AGENT) < target)
      __builtin_amdgcn_s_sleep(2);
  }
  __syncthreads();
}

// MFMA 16x16x32 bf16: A/B frag: lane holds row lane&15, 8 contiguous k at
// q*8 (q=lane>>4) within each 32-k slice; C/D: col=lane&15, row=q*4+reg.

// ================= layer-1 block: h-tile = bid*16 =================
// LDS: w bf16 [16][1032] @0 (33024); scr f32 [16][68] @65792
__device__ void l1_work(int t, int bid, int tid, float* __restrict__ out,
                        char* __restrict__ ws, short* w, float* scr,
                        float4v& v1, float4v& tr1) {
  const int h0 = bid * 16, wv = tid >> 6, lane = tid & 63;
  const int col = lane & 15, q = lane >> 4;

  // ---- gemm1: cur1[64b x 16h]; A = xbf (direct coherent frags), B = w (LDS)
  const short* xbf = (const short*)(ws + WS_XBF) + (t & 1) * (BB * INN);
  const int arow = (wv * 16 + col) * INN;
  float4v acc = {0.f, 0.f, 0.f, 0.f};
#pragma unroll
  for (int half = 0; half < 2; ++half) {
    u64 fa[32];
#pragma unroll
    for (int cc = 0; cc < 16; ++cc) {   // cc = chunk*4+kk over 4 chunks of 128
      int k = (half * 4 + (cc >> 2)) * 128 + (cc & 3) * 32 + q * 8;
      const short* p = &xbf[arow + k];
      fa[cc * 2] = cld(p);
      fa[cc * 2 + 1] = cld(p + 4);
    }
#pragma unroll
    for (int cc = 0; cc < 16; ++cc) {
      int k = (half * 4 + (cc >> 2)) * 128 + (cc & 3) * 32 + q * 8;
      short8v bf = *(const short8v*)&w[col * 1032 + k];
      acc = __builtin_amdgcn_mfma_f32_16x16x32_bf16(mk8(fa[cc * 2], fa[cc * 2 + 1]),
                                                    bf, acc, 0, 0, 0);
    }
  }

  // ---- LIF1 + publish l1 spikes (coherent) + tr1 to scr
  short* l1b = (short*)(ws + WS_L1B) + (t & 1) * (BB * HIDD);
  short* l1trT = (short*)(ws + WS_L1TRT) + (t & 1) * (HIDD * BB);
#pragma unroll
  for (int r = 0; r < 4; ++r) {
    float v = ALPHAF * v1[r] + SCLF * acc[r];
    float z = v > 1.0f ? 1.0f : 0.0f;
    v -= z;
    v1[r] = v;
    tr1[r] = DECAYF * tr1[r] + (1.0f - DECAYF) * z;
    int b = wv * 16 + q * 4 + r;
    out[O_L1SEQ + (b * TT + t) * HIDD + h0 + col] = z;
    cst16(&l1b[b * HIDD + h0 + col], f2bf(z));
    scr[col * 68 + b] = tr1[r];
    if (t == TT - 1) {
      out[O_V1 + b * HIDD + h0 + col] = v1[r];
      out[O_L1TR + b * HIDD + h0 + col] = tr1[r];
    }
  }
  __syncthreads();
  {  // publish l1_tr^T (16 h x 64 b), coherent 8B stores
    int idx = tid * 4, hl = idx >> 6, b0 = idx & 63;
    union { short4 s; u64 u; } cv;
    cv.s.x = f2bf(scr[hl * 68 + b0 + 0]);
    cv.s.y = f2bf(scr[hl * 68 + b0 + 1]);
    cv.s.z = f2bf(scr[hl * 68 + b0 + 2]);
    cv.s.w = f2bf(scr[hl * 68 + b0 + 3]);
    cst(&l1trT[(h0 + hl) * 64 + b0], cv.u);
  }

  // ---- outer1: w_in(LDS) update; B = in_tr^T (direct coherent frags), K=64
  const short* intrT = (const short*)(ws + WS_INTRT) + (t & 1) * (INN * BB);
  short8v afu[2];
#pragma unroll
  for (int kk = 0; kk < 2; ++kk) {
    short8v a;
#pragma unroll
    for (int j = 0; j < 8; ++j) a[j] = f2bf(scr[col * 68 + kk * 32 + q * 8 + j]);
    afu[kk] = a;
  }
  const float c0 = 1.0f - LRF * WDF, c1 = LRF / 64.0f;
#pragma unroll
  for (int half = 0; half < 2; ++half) {  // 8 ci total, 4 per half
    u64 fb[32];
#pragma unroll
    for (int cc = 0; cc < 16; ++cc) {     // cc = (ci_l*2 + j)*2 + kk
      int ci = half * 4 + (cc >> 2);
      int nt = wv * 2 + ((cc >> 1) & 1);
      int kk = cc & 1;
      const short* p = &intrT[(ci * 128 + nt * 16 + col) * 64 + kk * 32 + q * 8];
      fb[cc * 2] = cld(p);
      fb[cc * 2 + 1] = cld(p + 4);
    }
#pragma unroll
    for (int cij = 0; cij < 8; ++cij) {   // ci_l = cij>>1, j = cij&1
      int ci = half * 4 + (cij >> 1);
      int nt = wv * 2 + (cij & 1);
      float4v au = {0.f, 0.f, 0.f, 0.f};
#pragma unroll
      for (int kk = 0; kk < 2; ++kk) {
        int cc = cij * 2 + kk;
        au = __builtin_amdgcn_mfma_f32_16x16x32_bf16(afu[kk],
                 mk8(fb[cc * 2], fb[cc * 2 + 1]), au, 0, 0, 0);
      }
#pragma unroll
      for (int r = 0; r < 4; ++r) {
        int hrow = q * 4 + r, icol = ci * 128 + nt * 16 + col;
        float ow = bf2f(w[hrow * 1032 + icol]);
        w[hrow * 1032 + icol] = f2bf(ow * c0 + c1 * au[r]);
      }
    }
  }
}

// ================= layer-2 block: o-tile = idx16*16 =================
// LDS: w2b bf16 [16][2056] @0 (65792); scr f32 [16][68] @65792
__device__ void l2_work(int tp, int idx16, int tid, float* __restrict__ out,
                        char* __restrict__ ws, float* __restrict__ w_hid,
                        short* w2b, float* scr, float4v& v2, float4v& tr2) {
  const int o0 = idx16 * 16, wv = tid >> 6, lane = tid & 63;
  const int col = lane & 15, q = lane >> 4;

  // ---- refresh bf16 copy of w_hid rows (plain cached loads; block-private)
#pragma unroll
  for (int rnd = 0; rnd < 16; ++rnd) {
    int idx = rnd * 2048 + tid * 8, r = idx >> 11, c = idx & 2047;
    const float* p = &w_hid[(o0 + r) * HIDD + c];
    float4 a = *(const float4*)p, b = *(const float4*)(p + 4);
    short8v sv;
    sv[0] = f2bf(a.x); sv[1] = f2bf(a.y); sv[2] = f2bf(a.z); sv[3] = f2bf(a.w);
    sv[4] = f2bf(b.x); sv[5] = f2bf(b.y); sv[6] = f2bf(b.z); sv[7] = f2bf(b.w);
    *(short8v*)&w2b[r * 2056 + c] = sv;
  }
  __syncthreads();

  // ---- gemm2: cur2[64b x 16o]; A = l1b (direct coherent frags), B = w2b (LDS)
  const short* l1b = (const short*)(ws + WS_L1B) + (tp & 1) * (BB * HIDD);
  const int arow = (wv * 16 + col) * HIDD;
  float4v acc = {0.f, 0.f, 0.f, 0.f};
#pragma unroll
  for (int half = 0; half < 2; ++half) {  // 16 chunks of 128, 8 per half
    u64 fa[64];
#pragma unroll
    for (int cc = 0; cc < 32; ++cc) {     // cc = chunk_l*4 + kk
      int k = (half * 8 + (cc >> 2)) * 128 + (cc & 3) * 32 + q * 8;
      const short* p = &l1b[arow + k];
      fa[cc * 2] = cld(p);
      fa[cc * 2 + 1] = cld(p + 4);
    }
#pragma unroll
    for (int cc = 0; cc < 32; ++cc) {
      int k = (half * 8 + (cc >> 2)) * 128 + (cc & 3) * 32 + q * 8;
      short8v bf = *(const short8v*)&w2b[col * 2056 + k];
      acc = __builtin_amdgcn_mfma_f32_16x16x32_bf16(mk8(fa[cc * 2], fa[cc * 2 + 1]),
                                                    bf, acc, 0, 0, 0);
    }
  }

  // ---- LIF2
#pragma unroll
  for (int r = 0; r < 4; ++r) {
    float v = ALPHAF * v2[r] + SCLF * acc[r];
    float z = v > 1.0f ? 1.0f : 0.0f;
    v -= z;
    v2[r] = v;
    tr2[r] = DECAYF * tr2[r] + (1.0f - DECAYF) * z;
    int b = wv * 16 + q * 4 + r;
    out[O_L2SEQ + (b * TT + tp) * OUTT + o0 + col] = z;
    scr[col * 68 + b] = tr2[r];
    if (tp == TT - 1) {
      out[O_V2 + b * OUTT + o0 + col] = v2[r];
      out[O_L2TR + b * OUTT + o0 + col] = tr2[r];
    }
  }
  __syncthreads();

  // ---- outer2: w_hid RMW (plain, block-private); B = l1_tr^T (direct coherent)
  const short* l1trT = (const short*)(ws + WS_L1TRT) + (tp & 1) * (HIDD * BB);
  short8v afu[2];
#pragma unroll
  for (int kk = 0; kk < 2; ++kk) {
    short8v a;
#pragma unroll
    for (int j = 0; j < 8; ++j) a[j] = f2bf(scr[col * 68 + kk * 32 + q * 8 + j]);
    afu[kk] = a;
  }
  const float c0 = 1.0f - LRF * WDF, c1 = LRF / 64.0f;
#pragma unroll
  for (int half = 0; half < 2; ++half) {  // 16 ci, 8 per half
    u64 fb[64];
#pragma unroll
    for (int cc = 0; cc < 32; ++cc) {     // cc = (ci_l*2 + j)*2 + kk
      int ci = half * 8 + (cc >> 2);
      int nt = wv * 2 + ((cc >> 1) & 1);
      int kk = cc & 1;
      const short* p = &l1trT[(ci * 128 + nt * 16 + col) * 64 + kk * 32 + q * 8];
      fb[cc * 2] = cld(p);
      fb[cc * 2 + 1] = cld(p + 4);
    }
#pragma unroll
    for (int cij = 0; cij < 16; ++cij) {  // ci_l = cij>>1, j = cij&1
      int ci = half * 8 + (cij >> 1);
      int nt = wv * 2 + (cij & 1);
      float4v au = {0.f, 0.f, 0.f, 0.f};
#pragma unroll
      for (int kk = 0; kk < 2; ++kk) {
        int cc = cij * 2 + kk;
        au = __builtin_amdgcn_mfma_f32_16x16x32_bf16(afu[kk],
                 mk8(fb[cc * 2], fb[cc * 2 + 1]), au, 0, 0, 0);
      }
#pragma unroll
      for (int r = 0; r < 4; ++r) {
        float* p = &w_hid[(o0 + q * 4 + r) * HIDD + ci * 128 + nt * 16 + col];
        *p = *p * c0 + c1 * au[r];
      }
    }
  }
}

// ================= helper block: in_tr in LDS; publish xbf(tt) + in_tr^T(tt) ====
// LDS: intr f32 [64][132] @0 (33792)
__device__ void helper_work(int tt, int hidx, int tid, const float* __restrict__ x,
                            char* __restrict__ ws, float* intr) {
  const int i0 = hidx * 128;
  short* xbf = (short*)(ws + WS_XBF) + (tt & 1) * (BB * INN);
  short* intrT = (short*)(ws + WS_INTRT) + (tt & 1) * (INN * BB);
#pragma unroll
  for (int rnd = 0; rnd < 4; ++rnd) {
    int idx = rnd * 2048 + tid * 8, b = idx >> 7, c = idx & 127;
    const float* xs = &x[(b * TT + tt) * INN + i0 + c];
    float4 xa = *(const float4*)xs, xb = *(const float4*)(xs + 4);
    // publish x_t as bf16 (exact: spikes are 0/1)
    union { short4 s; u64 u; } s0, s1;
    s0.s.x = f2bf(xa.x); s0.s.y = f2bf(xa.y); s0.s.z = f2bf(xa.z); s0.s.w = f2bf(xa.w);
    s1.s.x = f2bf(xb.x); s1.s.y = f2bf(xb.y); s1.s.z = f2bf(xb.z); s1.s.w = f2bf(xb.w);
    cst(&xbf[b * INN + i0 + c], s0.u);
    cst(&xbf[b * INN + i0 + c + 4], s1.u);
    float* ip = &intr[b * 132 + c];
    float4 p1 = *(const float4*)ip, p2 = *(const float4*)(ip + 4);
    float4 n1, n2;
    n1.x = DECAYF * p1.x + (1.0f - DECAYF) * xa.x;
    n1.y = DECAYF * p1.y + (1.0f - DECAYF) * xa.y;
    n1.z = DECAYF * p1.z + (1.0f - DECAYF) * xa.z;
    n1.w = DECAYF * p1.w + (1.0f - DECAYF) * xa.w;
    n2.x = DECAYF * p2.x + (1.0f - DECAYF) * xb.x;
    n2.y = DECAYF * p2.y + (1.0f - DECAYF) * xb.y;
    n2.z = DECAYF * p2.z + (1.0f - DECAYF) * xb.z;
    n2.w = DECAYF * p2.w + (1.0f - DECAYF) * xb.w;
    *(float4*)ip = n1;
    *(float4*)(ip + 4) = n2;
  }
  __syncthreads();
#pragma unroll
  for (int rnd = 0; rnd < 4; ++rnd) {
    int idx = rnd * 2048 + tid * 8, il = idx >> 6, b0 = idx & 63;
    union { short4 s; u64 u; } cv0, cv1;
    cv0.s.x = f2bf(intr[(b0 + 0) * 132 + il]);
    cv0.s.y = f2bf(intr[(b0 + 1) * 132 + il]);
    cv0.s.z = f2bf(intr[(b0 + 2) * 132 + il]);
    cv0.s.w = f2bf(intr[(b0 + 3) * 132 + il]);
    cv1.s.x = f2bf(intr[(b0 + 4) * 132 + il]);
    cv1.s.y = f2bf(intr[(b0 + 5) * 132 + il]);
    cv1.s.z = f2bf(intr[(b0 + 6) * 132 + il]);
    cv1.s.w = f2bf(intr[(b0 + 7) * 132 + il]);
    cst(&intrT[(i0 + il) * 64 + b0], cv0.u);
    cst(&intrT[(i0 + il) * 64 + b0 + 4], cv1.u);
  }
  __syncthreads();
}

// ---- init: zero the barrier counter ----
__global__ __launch_bounds__(64) void k_init(char* __restrict__ ws) {
  if (threadIdx.x == 0)
    __hip_atomic_store((unsigned*)(ws + WS_BAR), 0u,
                       __ATOMIC_RELAXED, __HIP_MEMORY_SCOPE_AGENT);
}

// 152 blocks <= 256 CUs -> every block gets its own CU; (256,1) frees VGPRs.
__global__ __launch_bounds__(256, 1) void k_persist(const float* __restrict__ x,
                                                    const float* __restrict__ w_in,
                                                    float* __restrict__ w_hid,
                                                    float* __restrict__ out,
                                                    char* __restrict__ ws) {
  __shared__ __align__(16) char smem[70144];
  const int bid = blockIdx.x, tid = threadIdx.x;
  unsigned* cnt = (unsigned*)(ws + WS_BAR);
  unsigned barord = 0;
  float4v vst = {0.f, 0.f, 0.f, 0.f};   // v1 / v2 (persistent, registers)
  float4v trs = {0.f, 0.f, 0.f, 0.f};   // l1_tr / l2_tr

  // ---- prologue
  if (bid < N_L1) {
    // load w_in tile [16h x 1024] f32 -> bf16 LDS (only global read of w_in)
    short* w = (short*)smem;
    int r = tid >> 4, c0 = (tid & 15) * 64;
    for (int cc = 0; cc < 64; cc += 4) {
      float4 u = *(const float4*)&w_in[(bid * 16 + r) * INN + c0 + cc];
      short4 s;
      s.x = f2bf(u.x); s.y = f2bf(u.y); s.z = f2bf(u.z); s.w = f2bf(u.w);
      *(short4*)&w[r * 1032 + c0 + cc] = s;
    }
  } else if (bid >= N_L1 + N_L2) {
    float* intr = (float*)smem;
    for (int e = tid; e < 64 * 132; e += 256) intr[e] = 0.f;
    __syncthreads();
    helper_work(0, bid - (N_L1 + N_L2), tid, x, ws, intr);
  }
  gbar(cnt, ++barord * NBLK, tid);

  // ---- supersteps: L1 does step t, L2 does step t-1, helpers prepare t+1
  for (int t = 0; t <= TT; ++t) {
    if (bid < N_L1) {
      if (t < TT)
        l1_work(t, bid, tid, out, ws, (short*)smem, (float*)(smem + 65792), vst, trs);
    } else if (bid < N_L1 + N_L2) {
      if (t >= 1)
        l2_work(t - 1, bid - N_L1, tid, out, ws, w_hid, (short*)smem,
                (float*)(smem + 65792), vst, trs);
    } else {
      if (t + 1 < TT)
        helper_work(t + 1, bid - (N_L1 + N_L2), tid, x, ws, (float*)smem);
    }
    if (t < TT) gbar(cnt, ++barord * NBLK, tid);
  }
}

extern "C" void kernel_launch(void* const* d_in, const int* in_sizes, int n_in,
                              void* d_out, int out_size, void* d_ws, size_t ws_size,
                              hipStream_t stream) {
  const float* x = (const float*)d_in[0];
  const float* w_in = (const float*)d_in[1];
  float* w_hid = (float*)d_in[2];   // mutated in place; harness restores each launch
  float* out = (float*)d_out;
  char* ws = (char*)d_ws;

  hipLaunchKernelGGL(k_init, dim3(1), dim3(64), 0, stream, ws);
  hipLaunchKernelGGL(k_persist, dim3(NBLK), dim3(256), 0, stream, x, w_in, w_hid, out, ws);
}